// Round 4
// baseline (1972.249 us; speedup 1.0000x reference)
//
#include <hip/hip_runtime.h>
#include <hip/hip_fp16.h>
#include <stdint.h>

// Problem constants: B=8, H=W=128, C=F=256, K=7, PAD=3, rs=128
typedef _Float16 half8 __attribute__((ext_vector_type(8)));   // 8 fp16 = 4 VGPR (MFMA A/B frag)
typedef _Float16 half2v __attribute__((ext_vector_type(2)));  // packed fp16 pair
typedef __attribute__((ext_vector_type(4))) float f32x4;      // MFMA C/D frag

__device__ __forceinline__ unsigned short f2h(float f) {      // RNE fp32->fp16
  __half h = __float2half(f);
  unsigned short u; __builtin_memcpy(&u, &h, 2); return u;
}
__device__ __forceinline__ unsigned pk2h(float a, float b) {  // RTZ packed pair (staging only)
  auto v = __builtin_amdgcn_cvt_pkrtz(a, b);
  unsigned u; __builtin_memcpy(&u, &v, 4); return u;
}
__device__ __forceinline__ half2v h2cast(unsigned u) {
  half2v v; __builtin_memcpy(&v, &u, 4); return v;
}

#if __has_builtin(__builtin_amdgcn_fdot2)
__device__ __forceinline__ float dot2(half2v a, half2v b, float c) {
  return __builtin_amdgcn_fdot2(a, b, c, false);
}
#else
__device__ __forceinline__ float dot2(half2v a, half2v b, float c) {
  return c + (float)a[0] * (float)b[0] + (float)a[1] * (float)b[1];
}
#endif

// async global->LDS, 16B per lane; lds dest = wave-uniform base + lane*16
__device__ __forceinline__ void gl_lds16(const void* g, void* l) {
  __builtin_amdgcn_global_load_lds(
      (const __attribute__((address_space(1))) void*)g,
      (__attribute__((address_space(3))) void*)l, 16, 0, 0);
}

// ---------------- Kernel 0: x fp32 -> fp16 (into d_out scratch region) ----------------
__global__ __launch_bounds__(256) void xcvt(const float* __restrict__ x,
                                            unsigned short* __restrict__ xh) {
  const size_t i = ((size_t)blockIdx.x * 256 + threadIdx.x) * 8;
  float4 a = *(const float4*)&x[i];
  float4 b = *(const float4*)&x[i + 4];
  uint4 o;
  o.x = pk2h(a.x, a.y); o.y = pk2h(a.z, a.w);
  o.z = pk2h(b.x, b.y); o.w = pk2h(b.z, b.w);
  *(uint4*)&xh[i] = o;
}

// ---------------- Kernel 1: weight transpose + fp32->fp16 ----------------
__global__ __launch_bounds__(256) void wconv(const float* __restrict__ Wq,
                                             const float* __restrict__ Wk,
                                             const float* __restrict__ Wv,
                                             unsigned short* __restrict__ Wb) {
  const int e = blockIdx.x;
  const int w = e >> 8;
  const int n = e & 255;
  const float* W = (w == 0) ? Wq : ((w == 1) ? Wk : Wv);
  const int k = threadIdx.x;
  Wb[(size_t)e * 256 + k] = f2h(W[(size_t)k * 256 + n]);
}

// ---------------- Kernel 2: fused QKV GEMM (fp16 MFMA, global_load_lds staging) ----------
__global__ __launch_bounds__(256) void qkv_gemm(const unsigned short* __restrict__ xh,
                                                const unsigned short* __restrict__ Wb,
                                                unsigned short* __restrict__ qkv) {
  __shared__ unsigned char ldsb[32768];

  const int tid = threadIdx.x;
  const int l = tid & 63, l15 = l & 15, l4 = l >> 4;
  const int wv = tid >> 6, wr = wv >> 1, wc = wv & 1;

  // XCD-aware chunked swizzle: 6144 blocks, 8 XCDs, 768 per XCD (bijective).
  const int pid = blockIdx.x;
  const int cid = (pid & 7) * 768 + (pid >> 3);
  const int by = cid / 6;
  const int bx = cid - by * 6;
  const size_t row0 = (size_t)by * 128;
  const int n0 = bx * 128;

  const int rbase0 = wv * 32, rbase1 = wv * 32 + 16;
  const int rA0 = rbase0 + (l >> 2), rA1 = rbase1 + (l >> 2);
  const int q0 = (l & 3) ^ ((rA0 >> 1) & 3), q1 = (l & 3) ^ ((rA1 >> 1) & 3);
  const unsigned short* gA0 = xh + (row0 + rA0) * 256 + q0 * 8;
  const unsigned short* gA1 = xh + (row0 + rA1) * 256 + q1 * 8;
  const unsigned short* gB0 = Wb + (size_t)(n0 + rA0) * 256 + q0 * 8;
  const unsigned short* gB1 = Wb + (size_t)(n0 + rA1) * 256 + q1 * 8;

  f32x4 acc[4][4] = {};

  auto stage = [&](int s, int d) {
    gl_lds16(gA0 + s * 32, &ldsb[d * 8192 + rbase0 * 64]);
    gl_lds16(gA1 + s * 32, &ldsb[d * 8192 + rbase1 * 64]);
    gl_lds16(gB0 + s * 32, &ldsb[16384 + d * 8192 + rbase0 * 64]);
    gl_lds16(gB1 + s * 32, &ldsb[16384 + d * 8192 + rbase1 * 64]);
  };

  stage(0, 0);
  __syncthreads();

  for (int s = 0; s < 8; ++s) {
    const int d = s & 1;
    if (s < 7) stage(s + 1, d ^ 1);
    half8 af[4], bf[4];
#pragma unroll
    for (int m = 0; m < 4; ++m) {
      const int r = wr * 64 + m * 16 + l15;
      af[m] = *(const half8*)&ldsb[d * 8192 + r * 64 + ((l4 ^ ((r >> 1) & 3)) * 16)];
    }
#pragma unroll
    for (int n = 0; n < 4; ++n) {
      const int r = wc * 64 + n * 16 + l15;
      bf[n] = *(const half8*)&ldsb[16384 + d * 8192 + r * 64 + ((l4 ^ ((r >> 1) & 3)) * 16)];
    }
#pragma unroll
    for (int n = 0; n < 4; ++n)
#pragma unroll
      for (int m = 0; m < 4; ++m)
        acc[m][n] = __builtin_amdgcn_mfma_f32_16x16x32_f16(af[m], bf[n], acc[m][n], 0, 0, 0);
    __syncthreads();
  }

  // Epilogue: C/D mapping col=lane&15, row=(lane>>4)*4+reg (m89-verified)
#pragma unroll
  for (int m = 0; m < 4; ++m)
#pragma unroll
    for (int n = 0; n < 4; ++n) {
      const int ng = n0 + wc * 64 + n * 16 + l15;
      unsigned short* op = qkv + (size_t)(ng >> 8) * 33554432 + (ng & 255);
#pragma unroll
      for (int r = 0; r < 4; ++r) {
        const size_t grow = row0 + wr * 64 + m * 16 + l4 * 4 + r;
        op[grow * 256] = f2h(acc[m][n][r]);
      }
    }
}

// ---------------- Kernel 2b: per-pixel relative-position projections ----------------
__global__ __launch_bounds__(256) void qrel(const unsigned short* __restrict__ q,
                                            const float* __restrict__ relx,
                                            const float* __restrict__ rely,
                                            unsigned short* __restrict__ qr) {
  __shared__ unsigned wpk[896];  // [0..447] x-pairs, [448..895] y-pairs; wpk[c2*7+j]
  for (int i = threadIdx.x; i < 896; i += 256) {
    const int hf = (i >= 448) ? 1 : 0;
    const int r = i - hf * 448;
    const int c2 = r / 7, j = r - c2 * 7;
    const float* R = hf ? rely : relx;
    wpk[i] = pk2h(R[(2 * c2) * 7 + j], R[(2 * c2 + 1) * 7 + j]);
  }
  __syncthreads();
  const size_t pix = (size_t)blockIdx.x * 256 + threadIdx.x;
  const uint4* qp = (const uint4*)(q + pix * 256);  // 32 uint4 = 256 fp16 channels
  float ax[7] = {0, 0, 0, 0, 0, 0, 0}, ay[7] = {0, 0, 0, 0, 0, 0, 0};
#pragma unroll
  for (int g = 0; g < 32; ++g) {
    const uint4 u = qp[g];
    const int c2b = (g & 15) * 4;
    if (g < 16) {
#pragma unroll
      for (int j = 0; j < 7; ++j) {
        float s = ax[j];
        s = dot2(h2cast(u.x), h2cast(wpk[(c2b + 0) * 7 + j]), s);
        s = dot2(h2cast(u.y), h2cast(wpk[(c2b + 1) * 7 + j]), s);
        s = dot2(h2cast(u.z), h2cast(wpk[(c2b + 2) * 7 + j]), s);
        s = dot2(h2cast(u.w), h2cast(wpk[(c2b + 3) * 7 + j]), s);
        ax[j] = s;
      }
    } else {
#pragma unroll
      for (int j = 0; j < 7; ++j) {
        float s = ay[j];
        s = dot2(h2cast(u.x), h2cast(wpk[448 + (c2b + 0) * 7 + j]), s);
        s = dot2(h2cast(u.y), h2cast(wpk[448 + (c2b + 1) * 7 + j]), s);
        s = dot2(h2cast(u.z), h2cast(wpk[448 + (c2b + 2) * 7 + j]), s);
        s = dot2(h2cast(u.w), h2cast(wpk[448 + (c2b + 3) * 7 + j]), s);
        ay[j] = s;
      }
    }
  }
  uint4 o0, o1;
  o0.x = pk2h(ax[0], ax[1]); o0.y = pk2h(ax[2], ax[3]);
  o0.z = pk2h(ax[4], ax[5]); o0.w = pk2h(ax[6], ay[0]);
  o1.x = pk2h(ay[1], ay[2]); o1.y = pk2h(ay[3], ay[4]);
  o1.z = pk2h(ay[5], ay[6]); o1.w = 0;
  uint4* dst = (uint4*)(qr + pix * 512);
  dst[0] = o0; dst[1] = o1;
}

// ---------------- Kernel 3: fused windowed attention ----------------
// v5: pipe-split tap reads. Post-mortems: v3 (async dbuf, 8 waves/CU) == baseline 167us
// -> LDS-read-pipe-bound (8w x 196 b128 x 12cyc x 16 phases ~ 125us). v4 (2px/thread)
// cut LDS traffic 1.75x but forced 1 wave/SIMD -> latency-exposed, 230us. Constraint:
// need >= 2 waves/SIMD AND less LDS-pipe traffic.
// Fix: split each tap's 4 planes across TWO pipes. Planes 0-1 (ch 0-15) staged in LDS
// (v3 path, conflict-free b128); planes 2-3 (ch 16-31) read per-tap DIRECTLY from
// global: one pixel-chunk's 32 ch = exactly one 64B line, halo working set = 532
// lines = 34KB (L1/L2-resident; 49x re-reads are cache hits, not HBM). LDS pipe and
// VMEM pipe run concurrently: 9.4K + ~12.5K cyc/chunk overlapped vs 18.8K serial.
// OOB taps: exec-masked predicated loads (zeros), matching zeroed LDS halo.
// Geometry unchanged from v3: 8x32 tile, grid 512, 2 blocks/CU, 8 waves/CU; LDS
// shrinks 68KB -> 34KB; staging instrs halve.
__global__ __launch_bounds__(256) void attn(const unsigned short* __restrict__ qkv,
                                            const float* __restrict__ bias,
                                            const unsigned short* __restrict__ qrelb,
                                            float* __restrict__ out) {
  __shared__ unsigned short kv[2][2][4256];  // 2 buf x 2 planes x 532 slots*8 = 34048 B

  const int tid = threadIdx.x;
  const int col = tid & 31, row = tid >> 5;

  const int pid = blockIdx.x;
  const int cid = (pid & 7) * 64 + (pid >> 3);   // XCD-chunked (512 = 8*64, bijective)
  const int ht = cid & 15, wt = (cid >> 4) & 3, b = cid >> 6;

  const int h = ht * 8 + row, w = wt * 32 + col;
  const size_t pix = (size_t)((b * 128 + h) * 128 + w);
  const int pbase = row * 38 + col;              // this thread's halo-pixel index

  const unsigned short* qb = qkv;
  const unsigned short* kb = qkv + 33554432;
  const unsigned short* vb = qkv + 67108864;

  // global tap addressing: top-left tap pixel index (may be arithmetically OOB; only
  // dereferenced under the validity mask)
  const long long pixbase = (long long)(b * 128 + h - 3) * 128 + (w - 3);

  // staging geometry: thread covers halo px tid, tid+256, tid+512 (532 total)
  const int pr0 = tid / 38, pc0 = tid - pr0 * 38;
  const int gh0 = ht * 8 + pr0 - 3, gw0 = wt * 32 + pc0 - 3;
  const bool ok0 = ((unsigned)gh0 < 128u) && ((unsigned)gw0 < 128u);
  const long long go0 = ((long long)((b * 128 + gh0) * 128 + gw0)) * 256;  // shorts

  const int p1 = tid + 256;
  const int pr1 = p1 / 38, pc1 = p1 - pr1 * 38;
  const int gh1 = ht * 8 + pr1 - 3, gw1 = wt * 32 + pc1 - 3;
  const bool ok1 = ((unsigned)gh1 < 128u) && ((unsigned)gw1 < 128u);
  const long long go1 = ((long long)((b * 128 + gh1) * 128 + gw1)) * 256;

  const int p2 = tid + 512;
  const int pr2 = p2 / 38, pc2 = p2 - pr2 * 38;
  const int gh2 = ht * 8 + pr2 - 3, gw2 = wt * 32 + pc2 - 3;
  const bool ok2 = (p2 < 532) && ((unsigned)gh2 < 128u) && ((unsigned)gw2 < 128u);
  const long long go2 = ((long long)((b * 128 + gh2) * 128 + gw2)) * 256;

  const int wb8 = (tid >> 6) * 512;  // wave's pixel-group base * 8 shorts

  // async stage of chunk c planes 0-1 (ch 0-15) into buffer d (no registers, no waits)
  auto stage = [&](const unsigned short* base, int c, int d) {
#pragma unroll
    for (int g = 0; g < 2; ++g) {
      if (ok0) gl_lds16(base + go0 + c * 32 + g * 8, &kv[d][g][wb8]);
      if (ok1) gl_lds16(base + go1 + c * 32 + g * 8, &kv[d][g][2048 + wb8]);
      if (ok2) gl_lds16(base + go2 + c * 32 + g * 8, &kv[d][g][4096]);
    }
  };

  // zero the static OOB halo slots once, for both buffers (gl_lds never writes them)
  {
    const uint4 z = make_uint4(0u, 0u, 0u, 0u);
    for (int p = tid; p < 532; p += 256) {
      const int pr = p / 38, pc = p - pr * 38;
      const int gh = ht * 8 + pr - 3, gw = wt * 32 + pc - 3;
      if (!((unsigned)gh < 128u && (unsigned)gw < 128u)) {
#pragma unroll
        for (int d = 0; d < 2; ++d)
#pragma unroll
          for (int g = 0; g < 2; ++g)
            *(uint4*)&kv[d][g][p * 8] = z;
      }
    }
  }

  // qrel: 14 fp16 at this pixel's out-slot head (written by qrel; we overwrite later)
  float qx[7], qy[7];
  {
    const uint4* rp = (const uint4*)(qrelb + pix * 512);
    uint4 r0 = rp[0], r1 = rp[1];
    half2v a0 = h2cast(r0.x), a1 = h2cast(r0.y), a2 = h2cast(r0.z), a3 = h2cast(r0.w);
    half2v b0 = h2cast(r1.x), b1 = h2cast(r1.y), b2 = h2cast(r1.z);
    qx[0] = a0[0]; qx[1] = a0[1]; qx[2] = a1[0]; qx[3] = a1[1];
    qx[4] = a2[0]; qx[5] = a2[1]; qx[6] = a3[0];
    qy[0] = a3[1]; qy[1] = b0[0]; qy[2] = b0[1]; qy[3] = b1[0];
    qy[4] = b1[1]; qy[5] = b2[0]; qy[6] = b2[1];
  }

  stage(kb, 0, 0);
  __syncthreads();   // implicit vmcnt(0): chunk-0 K staged + OOB zeros visible

  float sc[49];
#pragma unroll
  for (int t = 0; t < 49; ++t) sc[t] = 0.0f;

  // ---- Phase A: scores (double-buffered, one barrier per chunk) ----
  for (int s = 0; s < 8; ++s) {
    const int d = s & 1;
    // issue next stage NOW; its latency hides under the 49-tap compute below
    stage(s < 7 ? kb : vb, s < 7 ? s + 1 : 0, d ^ 1);
    const uint4* qsrc = (const uint4*)(qb + pix * 256 + s * 32);
    uint4 u0 = qsrc[0], u1 = qsrc[1], u2 = qsrc[2], u3 = qsrc[3];
    half2v qh[16];
    qh[0] = h2cast(u0.x); qh[1] = h2cast(u0.y); qh[2] = h2cast(u0.z); qh[3] = h2cast(u0.w);
    qh[4] = h2cast(u1.x); qh[5] = h2cast(u1.y); qh[6] = h2cast(u1.z); qh[7] = h2cast(u1.w);
    qh[8] = h2cast(u2.x); qh[9] = h2cast(u2.y); qh[10] = h2cast(u2.z); qh[11] = h2cast(u2.w);
    qh[12] = h2cast(u3.x); qh[13] = h2cast(u3.y); qh[14] = h2cast(u3.z); qh[15] = h2cast(u3.w);
    __builtin_amdgcn_s_setprio(1);
#pragma unroll
    for (int i = 0; i < 7; ++i) {
      const long long roff = (pixbase + i * 128) * 256 + s * 32 + 16;
      const bool vr = (unsigned)(h + i - 3) < 128u;
#pragma unroll
      for (int j = 0; j < 7; ++j) {
        const int q8 = (pbase + i * 38 + j) * 8;
        uint4 k0 = *(const uint4*)&kv[d][0][q8];
        uint4 k1 = *(const uint4*)&kv[d][1][q8];
        uint4 k2 = make_uint4(0u, 0u, 0u, 0u), k3 = make_uint4(0u, 0u, 0u, 0u);
        if (vr && (unsigned)(w + j - 3) < 128u) {
          const uint4* gp = (const uint4*)(kb + roff + j * 256);
          k2 = gp[0]; k3 = gp[1];
        }
        float s2 = sc[i * 7 + j];
        s2 = dot2(h2cast(k0.x), qh[0], s2);  s2 = dot2(h2cast(k0.y), qh[1], s2);
        s2 = dot2(h2cast(k0.z), qh[2], s2);  s2 = dot2(h2cast(k0.w), qh[3], s2);
        s2 = dot2(h2cast(k1.x), qh[4], s2);  s2 = dot2(h2cast(k1.y), qh[5], s2);
        s2 = dot2(h2cast(k1.z), qh[6], s2);  s2 = dot2(h2cast(k1.w), qh[7], s2);
        s2 = dot2(h2cast(k2.x), qh[8], s2);  s2 = dot2(h2cast(k2.y), qh[9], s2);
        s2 = dot2(h2cast(k2.z), qh[10], s2); s2 = dot2(h2cast(k2.w), qh[11], s2);
        s2 = dot2(h2cast(k3.x), qh[12], s2); s2 = dot2(h2cast(k3.y), qh[13], s2);
        s2 = dot2(h2cast(k3.z), qh[14], s2); s2 = dot2(h2cast(k3.w), qh[15], s2);
        sc[i * 7 + j] = s2;
      }
    }
    __builtin_amdgcn_s_setprio(0);
    __syncthreads();   // staged next chunk visible; current buffer free for reuse
  }

  // ---- softmax over 49 (fp32, per thread); V chunk 0 already staged in buf 0 ----
#pragma unroll
  for (int i = 0; i < 7; ++i)
#pragma unroll
    for (int j = 0; j < 7; ++j) sc[i * 7 + j] += qx[j] + qy[i];
  float mx = sc[0];
#pragma unroll
  for (int t = 1; t < 49; ++t) mx = fmaxf(mx, sc[t]);
  float sum = 0.0f;
#pragma unroll
  for (int t = 0; t < 49; ++t) {
    float e = __expf(sc[t] - mx);
    sc[t] = e;
    sum += e;
  }
  const float invs = 1.0f / sum;
  unsigned pw[49];
#pragma unroll
  for (int t = 0; t < 49; ++t) {
    const unsigned short ph = f2h(sc[t] * invs);
    pw[t] = (unsigned)ph | ((unsigned)ph << 16);
  }

  // ---- Phase B: out = sum p*v + bias (same pipeline; parity continues at buf 0) ----
  for (int s = 0; s < 8; ++s) {
    const int d = s & 1;
    const int f0 = s * 32;
    if (s < 7) stage(vb, s + 1, d ^ 1);
    half2v acc[16];
#pragma unroll
    for (int a = 0; a < 16; ++a) acc[a] = half2v{(_Float16)0, (_Float16)0};
    __builtin_amdgcn_s_setprio(1);
#pragma unroll
    for (int i = 0; i < 7; ++i) {
      const long long roff = (pixbase + i * 128) * 256 + s * 32 + 16;
      const bool vr = (unsigned)(h + i - 3) < 128u;
#pragma unroll
      for (int j = 0; j < 7; ++j) {
        const int q8 = (pbase + i * 38 + j) * 8;
        uint4 v0 = *(const uint4*)&kv[d][0][q8];
        uint4 v1 = *(const uint4*)&kv[d][1][q8];
        uint4 v2 = make_uint4(0u, 0u, 0u, 0u), v3 = make_uint4(0u, 0u, 0u, 0u);
        if (vr && (unsigned)(w + j - 3) < 128u) {
          const uint4* gp = (const uint4*)(vb + roff + j * 256);
          v2 = gp[0]; v3 = gp[1];
        }
        const half2v p2h = h2cast(pw[i * 7 + j]);
        acc[0] += p2h * h2cast(v0.x);  acc[1] += p2h * h2cast(v0.y);
        acc[2] += p2h * h2cast(v0.z);  acc[3] += p2h * h2cast(v0.w);
        acc[4] += p2h * h2cast(v1.x);  acc[5] += p2h * h2cast(v1.y);
        acc[6] += p2h * h2cast(v1.z);  acc[7] += p2h * h2cast(v1.w);
        acc[8] += p2h * h2cast(v2.x);  acc[9] += p2h * h2cast(v2.y);
        acc[10] += p2h * h2cast(v2.z); acc[11] += p2h * h2cast(v2.w);
        acc[12] += p2h * h2cast(v3.x); acc[13] += p2h * h2cast(v3.y);
        acc[14] += p2h * h2cast(v3.z); acc[15] += p2h * h2cast(v3.w);
      }
    }
    __builtin_amdgcn_s_setprio(0);
#pragma unroll
    for (int fq = 0; fq < 8; ++fq) {
      float4 bv = *(const float4*)&bias[f0 + fq * 4];
      float4 o;
      o.x = (float)acc[fq * 2 + 0][0] + bv.x;
      o.y = (float)acc[fq * 2 + 0][1] + bv.y;
      o.z = (float)acc[fq * 2 + 1][0] + bv.z;
      o.w = (float)acc[fq * 2 + 1][1] + bv.w;
      *(float4*)&out[pix * 256 + f0 + fq * 4] = o;
    }
    if (s < 7) __syncthreads();
  }
}

extern "C" void kernel_launch(void* const* d_in, const int* in_sizes, int n_in,
                              void* d_out, int out_size, void* d_ws, size_t ws_size,
                              hipStream_t stream) {
  const float* x = (const float*)d_in[0];
  const float* Wq = (const float*)d_in[1];
  const float* Wk = (const float*)d_in[2];
  const float* Wv = (const float*)d_in[3];
  const float* relx = (const float*)d_in[4];
  const float* rely = (const float*)d_in[5];
  const float* bias = (const float*)d_in[6];
  float* out = (float*)d_out;

  // d_out doubles as scratch: xh (fp16 x) dead after qkv_gemm; qrel writes 32 B into each
  // pixel's out slot head, read by attn before that slot is overwritten.
  unsigned short* xh = (unsigned short*)d_out;
  unsigned short* qrl = (unsigned short*)d_out;
  // ws layout: Wb (fp16, 768*256 = 384 KB) | qkv (3 * 33554432 fp16 = 192 MB)
  unsigned short* Wb = (unsigned short*)d_ws;
  unsigned short* qkv = (unsigned short*)((char*)d_ws + 393216);

  xcvt<<<dim3(16384), dim3(256), 0, stream>>>(x, xh);
  wconv<<<dim3(768), dim3(256), 0, stream>>>(Wq, Wk, Wv, Wb);
  qkv_gemm<<<dim3(6144), dim3(256), 0, stream>>>(xh, Wb, qkv);
  qrel<<<dim3(512), dim3(256), 0, stream>>>(qkv, relx, rely, qrl);
  attn<<<dim3(512), dim3(256), 0, stream>>>(qkv, bias, qrl, out);
}

// Round 5
// 288.969 us; speedup vs baseline: 6.8251x; 6.8251x over previous
//
#include <hip/hip_runtime.h>
#include <hip/hip_fp16.h>
#include <stdint.h>

// Problem constants: B=8, H=W=128, C=F=256, K=7, PAD=3, rs=128
typedef _Float16 half8 __attribute__((ext_vector_type(8)));   // 8 fp16 = 4 VGPR (MFMA A/B frag)
typedef _Float16 half2v __attribute__((ext_vector_type(2)));  // packed fp16 pair
typedef __attribute__((ext_vector_type(4))) float f32x4;      // MFMA C/D frag

__device__ __forceinline__ unsigned short f2h(float f) {      // RNE fp32->fp16
  __half h = __float2half(f);
  unsigned short u; __builtin_memcpy(&u, &h, 2); return u;
}
__device__ __forceinline__ unsigned pk2h(float a, float b) {  // RTZ packed pair (staging only)
  auto v = __builtin_amdgcn_cvt_pkrtz(a, b);
  unsigned u; __builtin_memcpy(&u, &v, 4); return u;
}
__device__ __forceinline__ half2v h2cast(unsigned u) {
  half2v v; __builtin_memcpy(&v, &u, 4); return v;
}

#if __has_builtin(__builtin_amdgcn_fdot2)
__device__ __forceinline__ float dot2(half2v a, half2v b, float c) {
  return __builtin_amdgcn_fdot2(a, b, c, false);
}
#else
__device__ __forceinline__ float dot2(half2v a, half2v b, float c) {
  return c + (float)a[0] * (float)b[0] + (float)a[1] * (float)b[1];
}
#endif

// async global->LDS, 16B per lane; lds dest = wave-uniform base + lane*16
__device__ __forceinline__ void gl_lds16(const void* g, void* l) {
  __builtin_amdgcn_global_load_lds(
      (const __attribute__((address_space(1))) void*)g,
      (__attribute__((address_space(3))) void*)l, 16, 0, 0);
}

// ---------------- Kernel 0: x fp32 -> fp16 (into d_out scratch region) ----------------
__global__ __launch_bounds__(256) void xcvt(const float* __restrict__ x,
                                            unsigned short* __restrict__ xh) {
  const size_t i = ((size_t)blockIdx.x * 256 + threadIdx.x) * 8;
  float4 a = *(const float4*)&x[i];
  float4 b = *(const float4*)&x[i + 4];
  uint4 o;
  o.x = pk2h(a.x, a.y); o.y = pk2h(a.z, a.w);
  o.z = pk2h(b.x, b.y); o.w = pk2h(b.z, b.w);
  *(uint4*)&xh[i] = o;
}

// ---------------- Kernel 1: weight transpose + fp32->fp16 ----------------
__global__ __launch_bounds__(256) void wconv(const float* __restrict__ Wq,
                                             const float* __restrict__ Wk,
                                             const float* __restrict__ Wv,
                                             unsigned short* __restrict__ Wb) {
  const int e = blockIdx.x;
  const int w = e >> 8;
  const int n = e & 255;
  const float* W = (w == 0) ? Wq : ((w == 1) ? Wk : Wv);
  const int k = threadIdx.x;
  Wb[(size_t)e * 256 + k] = f2h(W[(size_t)k * 256 + n]);
}

// ---------------- Kernel 2: fused QKV GEMM (fp16 MFMA, global_load_lds staging) ----------
__global__ __launch_bounds__(256) void qkv_gemm(const unsigned short* __restrict__ xh,
                                                const unsigned short* __restrict__ Wb,
                                                unsigned short* __restrict__ qkv) {
  __shared__ unsigned char ldsb[32768];

  const int tid = threadIdx.x;
  const int l = tid & 63, l15 = l & 15, l4 = l >> 4;
  const int wv = tid >> 6, wr = wv >> 1, wc = wv & 1;

  // XCD-aware chunked swizzle: 6144 blocks, 8 XCDs, 768 per XCD (bijective).
  const int pid = blockIdx.x;
  const int cid = (pid & 7) * 768 + (pid >> 3);
  const int by = cid / 6;
  const int bx = cid - by * 6;
  const size_t row0 = (size_t)by * 128;
  const int n0 = bx * 128;

  const int rbase0 = wv * 32, rbase1 = wv * 32 + 16;
  const int rA0 = rbase0 + (l >> 2), rA1 = rbase1 + (l >> 2);
  const int q0 = (l & 3) ^ ((rA0 >> 1) & 3), q1 = (l & 3) ^ ((rA1 >> 1) & 3);
  const unsigned short* gA0 = xh + (row0 + rA0) * 256 + q0 * 8;
  const unsigned short* gA1 = xh + (row0 + rA1) * 256 + q1 * 8;
  const unsigned short* gB0 = Wb + (size_t)(n0 + rA0) * 256 + q0 * 8;
  const unsigned short* gB1 = Wb + (size_t)(n0 + rA1) * 256 + q1 * 8;

  f32x4 acc[4][4] = {};

  auto stage = [&](int s, int d) {
    gl_lds16(gA0 + s * 32, &ldsb[d * 8192 + rbase0 * 64]);
    gl_lds16(gA1 + s * 32, &ldsb[d * 8192 + rbase1 * 64]);
    gl_lds16(gB0 + s * 32, &ldsb[16384 + d * 8192 + rbase0 * 64]);
    gl_lds16(gB1 + s * 32, &ldsb[16384 + d * 8192 + rbase1 * 64]);
  };

  stage(0, 0);
  __syncthreads();

  for (int s = 0; s < 8; ++s) {
    const int d = s & 1;
    if (s < 7) stage(s + 1, d ^ 1);
    half8 af[4], bf[4];
#pragma unroll
    for (int m = 0; m < 4; ++m) {
      const int r = wr * 64 + m * 16 + l15;
      af[m] = *(const half8*)&ldsb[d * 8192 + r * 64 + ((l4 ^ ((r >> 1) & 3)) * 16)];
    }
#pragma unroll
    for (int n = 0; n < 4; ++n) {
      const int r = wc * 64 + n * 16 + l15;
      bf[n] = *(const half8*)&ldsb[16384 + d * 8192 + r * 64 + ((l4 ^ ((r >> 1) & 3)) * 16)];
    }
#pragma unroll
    for (int n = 0; n < 4; ++n)
#pragma unroll
      for (int m = 0; m < 4; ++m)
        acc[m][n] = __builtin_amdgcn_mfma_f32_16x16x32_f16(af[m], bf[n], acc[m][n], 0, 0, 0);
    __syncthreads();
  }

  // Epilogue: C/D mapping col=lane&15, row=(lane>>4)*4+reg (m89-verified)
#pragma unroll
  for (int m = 0; m < 4; ++m)
#pragma unroll
    for (int n = 0; n < 4; ++n) {
      const int ng = n0 + wc * 64 + n * 16 + l15;
      unsigned short* op = qkv + (size_t)(ng >> 8) * 33554432 + (ng & 255);
#pragma unroll
      for (int r = 0; r < 4; ++r) {
        const size_t grow = row0 + wr * 64 + m * 16 + l4 * 4 + r;
        op[grow * 256] = f2h(acc[m][n][r]);
      }
    }
}

// ---------------- Kernel 2b: per-pixel relative-position projections ----------------
__global__ __launch_bounds__(256) void qrel(const unsigned short* __restrict__ q,
                                            const float* __restrict__ relx,
                                            const float* __restrict__ rely,
                                            unsigned short* __restrict__ qr) {
  __shared__ unsigned wpk[896];  // [0..447] x-pairs, [448..895] y-pairs; wpk[c2*7+j]
  for (int i = threadIdx.x; i < 896; i += 256) {
    const int hf = (i >= 448) ? 1 : 0;
    const int r = i - hf * 448;
    const int c2 = r / 7, j = r - c2 * 7;
    const float* R = hf ? rely : relx;
    wpk[i] = pk2h(R[(2 * c2) * 7 + j], R[(2 * c2 + 1) * 7 + j]);
  }
  __syncthreads();
  const size_t pix = (size_t)blockIdx.x * 256 + threadIdx.x;
  const uint4* qp = (const uint4*)(q + pix * 256);  // 32 uint4 = 256 fp16 channels
  float ax[7] = {0, 0, 0, 0, 0, 0, 0}, ay[7] = {0, 0, 0, 0, 0, 0, 0};
#pragma unroll
  for (int g = 0; g < 32; ++g) {
    const uint4 u = qp[g];
    const int c2b = (g & 15) * 4;
    if (g < 16) {
#pragma unroll
      for (int j = 0; j < 7; ++j) {
        float s = ax[j];
        s = dot2(h2cast(u.x), h2cast(wpk[(c2b + 0) * 7 + j]), s);
        s = dot2(h2cast(u.y), h2cast(wpk[(c2b + 1) * 7 + j]), s);
        s = dot2(h2cast(u.z), h2cast(wpk[(c2b + 2) * 7 + j]), s);
        s = dot2(h2cast(u.w), h2cast(wpk[(c2b + 3) * 7 + j]), s);
        ax[j] = s;
      }
    } else {
#pragma unroll
      for (int j = 0; j < 7; ++j) {
        float s = ay[j];
        s = dot2(h2cast(u.x), h2cast(wpk[448 + (c2b + 0) * 7 + j]), s);
        s = dot2(h2cast(u.y), h2cast(wpk[448 + (c2b + 1) * 7 + j]), s);
        s = dot2(h2cast(u.z), h2cast(wpk[448 + (c2b + 2) * 7 + j]), s);
        s = dot2(h2cast(u.w), h2cast(wpk[448 + (c2b + 3) * 7 + j]), s);
        ay[j] = s;
      }
    }
  }
  uint4 o0, o1;
  o0.x = pk2h(ax[0], ax[1]); o0.y = pk2h(ax[2], ax[3]);
  o0.z = pk2h(ax[4], ax[5]); o0.w = pk2h(ax[6], ay[0]);
  o1.x = pk2h(ay[1], ay[2]); o1.y = pk2h(ay[3], ay[4]);
  o1.z = pk2h(ay[5], ay[6]); o1.w = 0;
  uint4* dst = (uint4*)(qr + pix * 512);
  dst[0] = o0; dst[1] = o1;
}

// ---------------- Kernel 3: fused windowed attention ----------------
// v6: pair-share LDS reads WITHOUT losing occupancy. Constraints learned:
//  (v3) LDS-read-pipe-bound at 8 waves/CU (125us of LDS time in 167us kernel)
//  (v4) 2px/thread cut LDS x0.571 but halved threads -> 1 wave/SIMD, latency-exposed
//  (v2/v5) per-tap global reads / register staging -> VGPR 256 spill disaster
// Fix: thread = (vertical pixel-pair, channel-half). 131072 threads (v3 occupancy),
// each serving 2 px x 128 ch. Window-row sharing: 8 halo rows x 7 cols x 2 planes =
// 112 b128/chunk serves both px (v3: 196) -> LDS traffic x0.571 at 8 waves/CU.
// Phase A: thread dots its 2 planes for both px; score partials combined via
// __shfl_xor(.,32) (lane l <-> l^32 = same pair, other half); softmax redundant in
// both halves. Phase B: chunk s owned by half s>>2 (half-wave exec mask); owner
// computes both px full 32 ch -> same x0.571 traffic, total VALU conserved.
// Tile 16x16 px (128 pairs x 2 halves = 256 thr), halo 22x22=484, plane-major dbuf
// kv[2][4][484*8] = 62KB -> 2 blocks/CU = 8 waves/CU. Grid 512, XCD-chunked.
__global__ __launch_bounds__(256) void attn(const unsigned short* __restrict__ qkv,
                                            const float* __restrict__ bias,
                                            const unsigned short* __restrict__ qrelb,
                                            float* __restrict__ out) {
  __shared__ unsigned short kv[2][4][3872];  // 2 buf x 4 planes x 484 slots*8 = 61952 B

  const int tid = threadIdx.x;
  const int wave = tid >> 6, lane = tid & 63;
  const int half = lane >> 5;                    // channel-half owner
  const int pi = lane & 31;                      // pair index within wave
  const int pr = wave * 2 + (pi >> 4);           // pair-row 0..7
  const int pcol = pi & 15;                      // pair col 0..15

  const int pid = blockIdx.x;
  const int cid = (pid & 7) * 64 + (pid >> 3);   // XCD-chunked (512 = 8*64, bijective)
  const int b = cid >> 6;
  const int t6 = cid & 63;
  const int ht = t6 >> 3, wt = t6 & 7;           // 8x8 tiles of 16x16

  const int hA = ht * 16 + 2 * pr;               // pixel A image row; B = hA+1
  const int w = wt * 16 + pcol;
  const size_t pixA = (size_t)((b * 128 + hA) * 128 + w);
  const size_t pixB = pixA + 128;

  const unsigned short* qb = qkv;
  const unsigned short* kb = qkv + 33554432;
  const unsigned short* vb = qkv + 67108864;

  // staging geometry: 484 halo slots (22x22), thread covers slot tid and tid+256
  const int pr0 = tid / 22, pc0 = tid - pr0 * 22;
  const int gh0 = ht * 16 + pr0 - 3, gw0 = wt * 16 + pc0 - 3;
  const bool ok0 = ((unsigned)gh0 < 128u) && ((unsigned)gw0 < 128u);
  const long long go0 = ((long long)((b * 128 + gh0) * 128 + gw0)) * 256;  // shorts

  const int p1 = tid + 256;
  const int pr1 = p1 / 22, pc1 = p1 - pr1 * 22;
  const int gh1 = ht * 16 + pr1 - 3, gw1 = wt * 16 + pc1 - 3;
  const bool ok1 = (p1 < 484) && ((unsigned)gh1 < 128u) && ((unsigned)gw1 < 128u);
  const long long go1 = ((long long)((b * 128 + gh1) * 128 + gw1)) * 256;

  const int wb8 = wave * 512;                    // wave slot base * 8 shorts

  // async stage of chunk c (all 4 planes) into buffer d (no registers, no waits)
  auto stage = [&](const unsigned short* base, int c, int d) {
#pragma unroll
    for (int g = 0; g < 4; ++g) {
      if (ok0) gl_lds16(base + go0 + c * 32 + g * 8, &kv[d][g][wb8]);
      if (ok1) gl_lds16(base + go1 + c * 32 + g * 8, &kv[d][g][2048 + wb8]);
    }
  };

  // zero the static OOB halo slots once, for both buffers (gl_lds never writes them)
  {
    const uint4 z = make_uint4(0u, 0u, 0u, 0u);
    for (int p = tid; p < 484; p += 256) {
      const int prh = p / 22, pch = p - prh * 22;
      const int gh = ht * 16 + prh - 3, gw = wt * 16 + pch - 3;
      if (!((unsigned)gh < 128u && (unsigned)gw < 128u)) {
#pragma unroll
        for (int d = 0; d < 2; ++d)
#pragma unroll
          for (int g = 0; g < 4; ++g)
            *(uint4*)&kv[d][g][p * 8] = z;
      }
    }
  }

  stage(kb, 0, 0);
  __syncthreads();   // implicit vmcnt(0): chunk-0 K staged + OOB zeros visible

  float scA[49], scB[49];
#pragma unroll
  for (int t = 0; t < 49; ++t) { scA[t] = 0.0f; scB[t] = 0.0f; }

  // ---- Phase A: score partials over this thread's 128 channels ----
  for (int s = 0; s < 8; ++s) {
    const int d = s & 1;
    stage(s < 7 ? kb : vb, s < 7 ? s + 1 : 0, d ^ 1);
    // q: this chunk's 16 channels of this thread's half, both pixels
    const uint4* qAp = (const uint4*)(qb + pixA * 256 + s * 32 + half * 16);
    const uint4* qBp = (const uint4*)(qb + pixB * 256 + s * 32 + half * 16);
    uint4 a0 = qAp[0], a1 = qAp[1];
    uint4 b0 = qBp[0], b1 = qBp[1];
    half2v qhA[8], qhB[8];
    qhA[0] = h2cast(a0.x); qhA[1] = h2cast(a0.y); qhA[2] = h2cast(a0.z); qhA[3] = h2cast(a0.w);
    qhA[4] = h2cast(a1.x); qhA[5] = h2cast(a1.y); qhA[6] = h2cast(a1.z); qhA[7] = h2cast(a1.w);
    qhB[0] = h2cast(b0.x); qhB[1] = h2cast(b0.y); qhB[2] = h2cast(b0.z); qhB[3] = h2cast(b0.w);
    qhB[4] = h2cast(b1.x); qhB[5] = h2cast(b1.y); qhB[6] = h2cast(b1.z); qhB[7] = h2cast(b1.w);
    __builtin_amdgcn_s_setprio(1);
#pragma unroll
    for (int u = 0; u < 8; ++u) {        // halo row = 2pr+u; A taps u<7, B taps u>=1
#pragma unroll
      for (int e = 0; e < 2; ++e) {      // this half's 2 planes
        const int g = half * 2 + e;
        uint4 kk[7];
#pragma unroll
        for (int j = 0; j < 7; ++j)
          kk[j] = *(const uint4*)&kv[d][g][((2 * pr + u) * 22 + pcol + j) * 8];
#pragma unroll
        for (int j = 0; j < 7; ++j) {
          if (u < 7) {
            float s2 = scA[u * 7 + j];
            s2 = dot2(h2cast(kk[j].x), qhA[e * 4 + 0], s2);
            s2 = dot2(h2cast(kk[j].y), qhA[e * 4 + 1], s2);
            s2 = dot2(h2cast(kk[j].z), qhA[e * 4 + 2], s2);
            s2 = dot2(h2cast(kk[j].w), qhA[e * 4 + 3], s2);
            scA[u * 7 + j] = s2;
          }
          if (u >= 1) {
            float s2 = scB[(u - 1) * 7 + j];
            s2 = dot2(h2cast(kk[j].x), qhB[e * 4 + 0], s2);
            s2 = dot2(h2cast(kk[j].y), qhB[e * 4 + 1], s2);
            s2 = dot2(h2cast(kk[j].z), qhB[e * 4 + 2], s2);
            s2 = dot2(h2cast(kk[j].w), qhB[e * 4 + 3], s2);
            scB[(u - 1) * 7 + j] = s2;
          }
        }
      }
    }
    __builtin_amdgcn_s_setprio(0);
    __syncthreads();
  }

  // ---- cross-half reduction: lane l + lane l^32 hold the two channel-halves ----
#pragma unroll
  for (int t = 0; t < 49; ++t) {
    scA[t] += __shfl_xor(scA[t], 32, 64);
    scB[t] += __shfl_xor(scB[t], 32, 64);
  }

  // ---- rel-pos + softmax (redundant in both halves; identical results) ----
  {
    const uint4* rp = (const uint4*)(qrelb + pixA * 512);
    uint4 r0 = rp[0], r1 = rp[1];
    half2v c0 = h2cast(r0.x), c1 = h2cast(r0.y), c2 = h2cast(r0.z), c3 = h2cast(r0.w);
    half2v c4 = h2cast(r1.x), c5 = h2cast(r1.y), c6 = h2cast(r1.z);
    float qx[7] = {c0[0], c0[1], c1[0], c1[1], c2[0], c2[1], c3[0]};
    float qy[7] = {c3[1], c4[0], c4[1], c5[0], c5[1], c6[0], c6[1]};
#pragma unroll
    for (int i = 0; i < 7; ++i)
#pragma unroll
      for (int j = 0; j < 7; ++j) scA[i * 7 + j] += qx[j] + qy[i];
  }
  {
    const uint4* rp = (const uint4*)(qrelb + pixB * 512);
    uint4 r0 = rp[0], r1 = rp[1];
    half2v c0 = h2cast(r0.x), c1 = h2cast(r0.y), c2 = h2cast(r0.z), c3 = h2cast(r0.w);
    half2v c4 = h2cast(r1.x), c5 = h2cast(r1.y), c6 = h2cast(r1.z);
    float qx[7] = {c0[0], c0[1], c1[0], c1[1], c2[0], c2[1], c3[0]};
    float qy[7] = {c3[1], c4[0], c4[1], c5[0], c5[1], c6[0], c6[1]};
#pragma unroll
    for (int i = 0; i < 7; ++i)
#pragma unroll
      for (int j = 0; j < 7; ++j) scB[i * 7 + j] += qx[j] + qy[i];
  }

  unsigned pwp[49];  // packed: low16 = pixel A weight, high16 = pixel B weight
  {
    float mxA = scA[0], mxB = scB[0];
#pragma unroll
    for (int t = 1; t < 49; ++t) { mxA = fmaxf(mxA, scA[t]); mxB = fmaxf(mxB, scB[t]); }
    float sA = 0.0f, sB = 0.0f;
#pragma unroll
    for (int t = 0; t < 49; ++t) {
      float eA = __expf(scA[t] - mxA); scA[t] = eA; sA += eA;
      float eB = __expf(scB[t] - mxB); scB[t] = eB; sB += eB;
    }
    const float iA = 1.0f / sA, iB = 1.0f / sB;
#pragma unroll
    for (int t = 0; t < 49; ++t)
      pwp[t] = (unsigned)f2h(scA[t] * iA) | ((unsigned)f2h(scB[t] * iB) << 16);
  }

  // ---- Phase B: out = sum p*v + bias. Chunk s owned by half s>>2 (exec-masked);
  //      owner computes BOTH pixels' full 32 chunk-channels. Parity continues at buf 0.
  for (int s = 0; s < 8; ++s) {
    const int d = s & 1;
    const int f0 = s * 32;
    if (s < 7) stage(vb, s + 1, d ^ 1);
    if (half == (s >> 2)) {
      half2v accA[16], accB[16];
#pragma unroll
      for (int a = 0; a < 16; ++a) {
        accA[a] = half2v{(_Float16)0, (_Float16)0};
        accB[a] = half2v{(_Float16)0, (_Float16)0};
      }
      __builtin_amdgcn_s_setprio(1);
#pragma unroll
      for (int u = 0; u < 8; ++u) {
#pragma unroll
        for (int g = 0; g < 4; ++g) {
          uint4 kk[7];
#pragma unroll
          for (int j = 0; j < 7; ++j)
            kk[j] = *(const uint4*)&kv[d][g][((2 * pr + u) * 22 + pcol + j) * 8];
#pragma unroll
          for (int j = 0; j < 7; ++j) {
            if (u < 7) {
              unsigned pa = pwp[u * 7 + j] & 0xffffu; pa |= pa << 16;
              const half2v p2 = h2cast(pa);
              accA[g * 4 + 0] += p2 * h2cast(kk[j].x);
              accA[g * 4 + 1] += p2 * h2cast(kk[j].y);
              accA[g * 4 + 2] += p2 * h2cast(kk[j].z);
              accA[g * 4 + 3] += p2 * h2cast(kk[j].w);
            }
            if (u >= 1) {
              unsigned pbv = pwp[(u - 1) * 7 + j] >> 16; pbv |= pbv << 16;
              const half2v p2 = h2cast(pbv);
              accB[g * 4 + 0] += p2 * h2cast(kk[j].x);
              accB[g * 4 + 1] += p2 * h2cast(kk[j].y);
              accB[g * 4 + 2] += p2 * h2cast(kk[j].z);
              accB[g * 4 + 3] += p2 * h2cast(kk[j].w);
            }
          }
        }
      }
      __builtin_amdgcn_s_setprio(0);
#pragma unroll
      for (int fq = 0; fq < 8; ++fq) {
        float4 bv = *(const float4*)&bias[f0 + fq * 4];
        float4 oA, oB;
        oA.x = (float)accA[fq * 2 + 0][0] + bv.x;
        oA.y = (float)accA[fq * 2 + 0][1] + bv.y;
        oA.z = (float)accA[fq * 2 + 1][0] + bv.z;
        oA.w = (float)accA[fq * 2 + 1][1] + bv.w;
        oB.x = (float)accB[fq * 2 + 0][0] + bv.x;
        oB.y = (float)accB[fq * 2 + 0][1] + bv.y;
        oB.z = (float)accB[fq * 2 + 1][0] + bv.z;
        oB.w = (float)accB[fq * 2 + 1][1] + bv.w;
        *(float4*)&out[pixA * 256 + f0 + fq * 4] = oA;
        *(float4*)&out[pixB * 256 + f0 + fq * 4] = oB;
      }
    }
    if (s < 7) __syncthreads();
  }
}

extern "C" void kernel_launch(void* const* d_in, const int* in_sizes, int n_in,
                              void* d_out, int out_size, void* d_ws, size_t ws_size,
                              hipStream_t stream) {
  const float* x = (const float*)d_in[0];
  const float* Wq = (const float*)d_in[1];
  const float* Wk = (const float*)d_in[2];
  const float* Wv = (const float*)d_in[3];
  const float* relx = (const float*)d_in[4];
  const float* rely = (const float*)d_in[5];
  const float* bias = (const float*)d_in[6];
  float* out = (float*)d_out;

  // d_out doubles as scratch: xh (fp16 x) dead after qkv_gemm; qrel writes 32 B into each
  // pixel's out slot head, read by attn before that slot is overwritten.
  unsigned short* xh = (unsigned short*)d_out;
  unsigned short* qrl = (unsigned short*)d_out;
  // ws layout: Wb (fp16, 768*256 = 384 KB) | qkv (3 * 33554432 fp16 = 192 MB)
  unsigned short* Wb = (unsigned short*)d_ws;
  unsigned short* qkv = (unsigned short*)((char*)d_ws + 393216);

  xcvt<<<dim3(16384), dim3(256), 0, stream>>>(x, xh);
  wconv<<<dim3(768), dim3(256), 0, stream>>>(Wq, Wk, Wv, Wb);
  qkv_gemm<<<dim3(6144), dim3(256), 0, stream>>>(xh, Wb, qkv);
  qrel<<<dim3(512), dim3(256), 0, stream>>>(qkv, relx, rely, qrl);
  attn<<<dim3(512), dim3(256), 0, stream>>>(qkv, bias, qrl, out);
}